// Round 2
// baseline (673.506 us; speedup 1.0000x reference)
//
#include <hip/hip_runtime.h>
#include <stdint.h>

// Analog MVM (aihwkit TorchSimulatorTile) for MI355X.
// input_ [8192,4096] f32, weight [4096,4096] f32, out [8192,4096] f32.
//
// R1 fix: JAX partitionable threefry 32-bit random bits are out0 ^ out1
// (jax/_src/prng.py _threefry_random_bits_partitionable), not out0 alone.

#define MM 8192
#define KK 4096
#define NN 4096
#define TOTAL_OUT ((size_t)MM * (size_t)NN)

typedef __attribute__((ext_vector_type(4))) float f32x4;
typedef __attribute__((ext_vector_type(8))) short bf16x8;
typedef __attribute__((ext_vector_type(8))) unsigned short u16x8;

#define R_IN_F ((float)(2.0 / 254.0))     // DAC grid step (f32 of python double)
#define R_OUT_F ((float)(24.0 / 510.0))   // ADC grid step

struct BmState {
  int done;
  float red_final;
  int viol[8];
};

// ---------------- Threefry-2x32-20 (exact JAX) ----------------
__host__ __device__ __forceinline__ uint32_t tf_rotl(uint32_t v, int r) {
  return (v << r) | (v >> (32 - r));
}

__host__ __device__ __forceinline__ void threefry2x32(uint32_t k0, uint32_t k1,
                                                      uint32_t x0, uint32_t x1,
                                                      uint32_t &o0, uint32_t &o1) {
  uint32_t ks2 = k0 ^ k1 ^ 0x1BD11BDAu;
  x0 += k0; x1 += k1;
#define TF_R(r) { x0 += x1; x1 = tf_rotl(x1, r); x1 ^= x0; }
  TF_R(13) TF_R(15) TF_R(26) TF_R(6)
  x0 += k1; x1 += ks2 + 1u;
  TF_R(17) TF_R(29) TF_R(16) TF_R(24)
  x0 += ks2; x1 += k0 + 2u;
  TF_R(13) TF_R(15) TF_R(26) TF_R(6)
  x0 += k0; x1 += k1 + 3u;
  TF_R(17) TF_R(29) TF_R(16) TF_R(24)
  x0 += k1; x1 += ks2 + 4u;
  TF_R(13) TF_R(15) TF_R(26) TF_R(6)
  x0 += ks2; x1 += k0 + 5u;
#undef TF_R
  o0 = x0; o1 = x1;
}

// XLA ErfInv32 (Giles polynomial, log1p form) — matches CPU XLA to ~1 ulp.
__device__ __forceinline__ float erfinv_xla(float x) {
  float w = -log1pf(-x * x);
  float p;
  if (w < 5.0f) {
    w = w - 2.5f;
    p = 2.81022636e-08f;
    p = fmaf(p, w, 3.43273939e-07f);
    p = fmaf(p, w, -3.5233877e-06f);
    p = fmaf(p, w, -4.39150654e-06f);
    p = fmaf(p, w, 0.00021858087f);
    p = fmaf(p, w, -0.00125372503f);
    p = fmaf(p, w, -0.00417768164f);
    p = fmaf(p, w, 0.246640727f);
    p = fmaf(p, w, 1.50140941f);
  } else {
    w = sqrtf(w) - 3.0f;
    p = -0.000200214257f;
    p = fmaf(p, w, 0.000100950558f);
    p = fmaf(p, w, 0.00134934322f);
    p = fmaf(p, w, -0.00367342844f);
    p = fmaf(p, w, 0.00573950773f);
    p = fmaf(p, w, -0.0076224613f);
    p = fmaf(p, w, 0.00943887047f);
    p = fmaf(p, w, 1.00167406f);
    p = fmaf(p, w, 2.83297682f);
  }
  return p * x;
}

// JAX uniform(-0.99999994, 1) -> sqrt(2)*erfinv -> *0.06
__device__ __forceinline__ float noise_from_bits(uint32_t bits) {
  uint32_t fb = (bits >> 9) | 0x3f800000u;
  float f = __uint_as_float(fb) - 1.0f;   // [0,1)
  const float lo = -0.99999994f;          // nextafter(-1,0) f32
  float u = f * 2.0f + lo;                // (maxval-minval) folds to exactly 2.0f
  u = fmaxf(lo, u);
  return 0.06f * (1.41421356f * erfinv_xla(u));
}

__device__ __forceinline__ unsigned short bf16_rne(float f) {
  uint32_t x = __float_as_uint(f);
  x += 0x7fffu + ((x >> 16) & 1u);
  return (unsigned short)(x >> 16);
}

// DAC: x = v*s; t = x/r; k = rint(t) clamped to ±127. Value = k (exact int, bf16-exact).
__device__ __forceinline__ float dac_quant(float v, float s) {
  float x = v * s;
  float t = x / R_IN_F;
  float k = rintf(t);
  return fminf(127.0f, fmaxf(-127.0f, k));
}

__device__ __forceinline__ u16x8 quant8(float4 a, float4 b, float s) {
  u16x8 o;
  o[0] = bf16_rne(dac_quant(a.x, s));
  o[1] = bf16_rne(dac_quant(a.y, s));
  o[2] = bf16_rne(dac_quant(a.z, s));
  o[3] = bf16_rne(dac_quant(a.w, s));
  o[4] = bf16_rne(dac_quant(b.x, s));
  o[5] = bf16_rne(dac_quant(b.y, s));
  o[6] = bf16_rne(dac_quant(b.z, s));
  o[7] = bf16_rne(dac_quant(b.w, s));
  return o;
}

__device__ __forceinline__ u16x8 conv8(float4 a, float4 b) {
  u16x8 o;
  o[0] = bf16_rne(a.x); o[1] = bf16_rne(a.y); o[2] = bf16_rne(a.z); o[3] = bf16_rne(a.w);
  o[4] = bf16_rne(b.x); o[5] = bf16_rne(b.y); o[6] = bf16_rne(b.z); o[7] = bf16_rne(b.w);
  return o;
}

// ---------------- kernels ----------------
__global__ void k_init(BmState *st) {
  if (threadIdx.x == 0) {
    st->done = 0;
    st->red_final = 0.0f;
    for (int i = 0; i < 8; ++i) st->viol[i] = 0;
  }
}

__global__ __launch_bounds__(256) void k_rowmax(const float *__restrict__ in,
                                                float *__restrict__ nm) {
  const int row = blockIdx.x;
  const float4 *r = (const float4 *)(in + (size_t)row * KK);
  const int t = threadIdx.x;
  float m = 0.0f;
#pragma unroll
  for (int i = 0; i < 4; ++i) {
    float4 v = r[t + i * 256];
    m = fmaxf(m, fmaxf(fmaxf(fabsf(v.x), fabsf(v.y)), fmaxf(fabsf(v.z), fabsf(v.w))));
  }
#pragma unroll
  for (int off = 32; off > 0; off >>= 1) m = fmaxf(m, __shfl_down(m, off));
  __shared__ float wm[4];
  if ((t & 63) == 0) wm[t >> 6] = m;
  __syncthreads();
  if (t == 0) {
    m = fmaxf(fmaxf(wm[0], wm[1]), fmaxf(wm[2], wm[3]));
    nm[row] = (m <= 0.0f) ? 1.0f : m;
  }
}

__global__ __launch_bounds__(256) void k_wconv(const float *__restrict__ w,
                                               unsigned short *__restrict__ wb) {
  const size_t idx = ((size_t)blockIdx.x * 256 + threadIdx.x) * 8;
  float4 a = *(const float4 *)(w + idx);
  float4 b = *(const float4 *)(w + idx + 4);
  *(u16x8 *)(wb + idx) = conv8(a, b);
}

__global__ __launch_bounds__(256) void k_quant(const float *__restrict__ in,
                                               const float *__restrict__ nm,
                                               unsigned short *__restrict__ ab,
                                               const BmState *__restrict__ st, float red) {
  if (st->done) return;
  const size_t idx = ((size_t)blockIdx.x * 256 + threadIdx.x) * 8;
  const int row = (int)(idx >> 12);
  const float s = 1.0f / (nm[row] * red);
  float4 a = *(const float4 *)(in + idx);
  float4 b = *(const float4 *)(in + idx + 4);
  *(u16x8 *)(ab + idx) = quant8(a, b, s);
}

__device__ __forceinline__ void async16(const void *g, void *l) {
  __builtin_amdgcn_global_load_lds((const __attribute__((address_space(1))) uint32_t *)g,
                                   (__attribute__((address_space(3))) uint32_t *)l,
                                   16, 0, 0);
}

// C = A(int-bf16) @ B(bf16)^T, both [rows][K] K-major. MODE 0: pre-staged buffers via
// global_load_lds. MODE 1: reg-staged straight from f32 inputs (quantize/convert inline).
template <int MODE>
__global__ __launch_bounds__(256) void k_gemm(
    const unsigned short *__restrict__ A, const unsigned short *__restrict__ B,
    const float *__restrict__ Af, const float *__restrict__ Bf,
    const float *__restrict__ nm, float red,
    float *__restrict__ C, const BmState *__restrict__ st) {
  if (st->done) return;
  __shared__ unsigned short As[128 * 64];
  __shared__ unsigned short Bs[128 * 64];
  const int tid = threadIdx.x;
  const int lane = tid & 63;
  const int wv = tid >> 6;
  const int wr = wv >> 1, wc = wv & 1;
  const int brow = blockIdx.y * 128;
  const int bcol = blockIdx.x * 128;

  f32x4 acc[4][4];
#pragma unroll
  for (int m = 0; m < 4; ++m)
#pragma unroll
    for (int n = 0; n < 4; ++n) acc[m][n] = (f32x4){0.f, 0.f, 0.f, 0.f};

  float sA[4];
  if constexpr (MODE == 1) {
#pragma unroll
    for (int i = 0; i < 4; ++i) {
      int u = i * 256 + tid;
      sA[i] = 1.0f / (nm[brow + (u >> 3)] * red);
    }
  }

  for (int kt = 0; kt < KK; kt += 64) {
    if constexpr (MODE == 0) {
#pragma unroll
      for (int i = 0; i < 4; ++i) {
        const int u0 = i * 256 + wv * 64;  // wave-uniform LDS base unit
        const int u = u0 + lane;
        const int r = u >> 3, k8 = (u & 7) * 8;
        async16(A + (size_t)(brow + r) * KK + kt + k8, (char *)As + (size_t)u0 * 16);
        async16(B + (size_t)(bcol + r) * KK + kt + k8, (char *)Bs + (size_t)u0 * 16);
      }
    } else {
#pragma unroll
      for (int i = 0; i < 4; ++i) {
        const int u = i * 256 + tid;
        const int r = u >> 3, k8 = (u & 7) * 8;
        {
          const float *g = Af + (size_t)(brow + r) * KK + kt + k8;
          float4 x = *(const float4 *)g, y = *(const float4 *)(g + 4);
          *(u16x8 *)(As + r * 64 + k8) = quant8(x, y, sA[i]);
        }
        {
          const float *g = Bf + (size_t)(bcol + r) * KK + kt + k8;
          float4 x = *(const float4 *)g, y = *(const float4 *)(g + 4);
          *(u16x8 *)(Bs + r * 64 + k8) = conv8(x, y);
        }
      }
    }
    __syncthreads();

    const int r16 = lane & 15;
    const int kg = (lane >> 4) * 8;
#pragma unroll
    for (int kk = 0; kk < 64; kk += 32) {
      bf16x8 af[4], bg[4];
#pragma unroll
      for (int m = 0; m < 4; ++m)
        af[m] = *(const bf16x8 *)(As + (wr * 64 + m * 16 + r16) * 64 + kk + kg);
#pragma unroll
      for (int n = 0; n < 4; ++n)
        bg[n] = *(const bf16x8 *)(Bs + (wc * 64 + n * 16 + r16) * 64 + kk + kg);
#pragma unroll
      for (int m = 0; m < 4; ++m)
#pragma unroll
        for (int n = 0; n < 4; ++n)
          acc[m][n] = __builtin_amdgcn_mfma_f32_16x16x32_bf16(af[m], bg[n], acc[m][n], 0, 0, 0);
    }
    __syncthreads();
  }

  const int c16 = lane & 15;
  const int q4 = (lane >> 4) * 4;
#pragma unroll
  for (int m = 0; m < 4; ++m) {
    const int row = brow + wr * 64 + m * 16 + q4;
#pragma unroll
    for (int n = 0; n < 4; ++n) {
      const int col = bcol + wc * 64 + n * 16 + c16;
      float *cp = C + (size_t)row * NN + col;
      cp[0 * (size_t)NN] = acc[m][n][0];
      cp[1 * (size_t)NN] = acc[m][n][1];
      cp[2 * (size_t)NN] = acc[m][n][2];
      cp[3 * (size_t)NN] = acc[m][n][3];
    }
  }
}

// epilogue: out = clip(quant(r_in*gemm + noise)) * nm * red; record clip violations.
__global__ __launch_bounds__(256) void k_epi(float *__restrict__ out,
                                             const float *__restrict__ nm,
                                             BmState *__restrict__ st, int pass, float red,
                                             uint32_t fk0, uint32_t fk1) {
  if (st->done) return;
  const size_t idx = ((size_t)blockIdx.x * 256 + threadIdx.x) * 8;
  const int row = (int)(idx >> 12);
  const float sc = nm[row] * red;
  float4 a = *(const float4 *)(out + idx);
  float4 b = *(const float4 *)(out + idx + 4);
  float v[8] = {a.x, a.y, a.z, a.w, b.x, b.y, b.z, b.w};
  bool bad = false;
#pragma unroll
  for (int j = 0; j < 8; ++j) {
    uint32_t w0, w1;
    // Partitionable threefry bits for element i (hi=0, lo=i): bits = out0 ^ out1.
    threefry2x32(fk0, fk1, 0u, (uint32_t)(idx + j), w0, w1);
    float o = R_IN_F * v[j] + noise_from_bits(w0 ^ w1);
    float q = rintf(o / R_OUT_F) * R_OUT_F;
    float z = o + (q - o);  // straight-through forward value
    bad = bad || (z > 12.0f) || (z < -12.0f);
    z = fminf(12.0f, fmaxf(-12.0f, z));
    v[j] = z * sc;
  }
  *(float4 *)(out + idx) = make_float4(v[0], v[1], v[2], v[3]);
  *(float4 *)(out + idx + 4) = make_float4(v[4], v[5], v[6], v[7]);
  unsigned long long vb = __ballot(bad ? 1 : 0);
  if (vb != 0ull && (threadIdx.x & 63) == 0) atomicOr(&st->viol[pass], 1);
}

__global__ void k_fin(BmState *st, int pass, float red) {
  if (st->done) return;
  bool ok = (st->viol[pass] == 0) || (red > 1000.0f) || (red > 31.75f);
  if (ok) {
    st->done = 1;
    st->red_final = red;
  }
}

// ---------------- launch ----------------
extern "C" void kernel_launch(void *const *d_in, const int *in_sizes, int n_in,
                              void *d_out, int out_size, void *d_ws, size_t ws_size,
                              hipStream_t stream) {
  const float *input = (const float *)d_in[0];
  const float *weight = (const float *)d_in[1];
  if (n_in >= 2 && in_sizes[0] < in_sizes[1]) {  // defensive: input is the bigger one
    const float *t = input; input = weight; weight = t;
  }
  float *out = (float *)d_out;
  char *ws = (char *)d_ws;
  BmState *st = (BmState *)ws;
  float *nm = (float *)(ws + 4096);
  unsigned short *Ab = (unsigned short *)(ws + 36864);
  unsigned short *Wb = Ab + (size_t)MM * KK;
  const size_t need = 36864 + ((size_t)MM * KK + (size_t)NN * KK) * 2;
  const bool fast = ws_size >= need;

  // fold_in(key(42), p) = threefry((0,42), (0,p)) computed on host
  uint32_t fk[8][2];
  for (int p = 1; p <= 6; ++p) threefry2x32(0u, 42u, 0u, (uint32_t)p, fk[p][0], fk[p][1]);

  k_init<<<dim3(1), dim3(64), 0, stream>>>(st);
  k_rowmax<<<dim3(MM), dim3(256), 0, stream>>>(input, nm);
  if (fast) k_wconv<<<dim3((NN * (size_t)KK) / 2048), dim3(256), 0, stream>>>(weight, Wb);

  float red = 1.0f;
  for (int p = 1; p <= 6; ++p, red *= 2.0f) {
    if (fast) {
      k_quant<<<dim3((MM * (size_t)KK) / 2048), dim3(256), 0, stream>>>(input, nm, Ab, st, red);
      k_gemm<0><<<dim3(NN / 128, MM / 128), dim3(256), 0, stream>>>(
          Ab, Wb, nullptr, nullptr, nm, red, out, st);
    } else {
      k_gemm<1><<<dim3(NN / 128, MM / 128), dim3(256), 0, stream>>>(
          nullptr, nullptr, input, weight, nm, red, out, st);
    }
    k_epi<<<dim3(TOTAL_OUT / 2048), dim3(256), 0, stream>>>(out, nm, st, p, red, fk[p][0], fk[p][1]);
    k_fin<<<dim3(1), dim3(1), 0, stream>>>(st, p, red);
  }
}